// Round 1
// baseline (68.245 us; speedup 1.0000x reference)
//
#include <hip/hip_runtime.h>

#define NUM_KNOTS 64
#define FEAT 128
#define NSEG 61   // interior segments: knots j/61, j=0..61

__device__ __forceinline__ float rcp_fast(float d) {
    // d is exactly 1.0f, 2.0f, or 3.0f here; v_rcp_f32 is exact for powers of 2
    // and ~1 ulp for 3.0 -- far below the test threshold.
    return __builtin_amdgcn_rcpf(d);
}

__global__ __launch_bounds__(256, 4) void bspline_kernel(
    const float* __restrict__ x,
    const float* __restrict__ cp,     // [64][128]
    const float* __restrict__ bias,   // [128]
    float* __restrict__ out,
    int n)
{
    // Stage control points in LDS: 64*128*4 = 32 KB. Word index j*128+f ->
    // bank = f%32; with lane-consecutive f that's 2-way aliasing = free (m136).
    __shared__ float s_cp[NUM_KNOTS * FEAT];
    {
        const float4* cp4 = (const float4*)cp;
        float4* s4 = (float4*)s_cp;
        #pragma unroll
        for (int i = threadIdx.x; i < NUM_KNOTS * FEAT / 4; i += 256)
            s4[i] = cp4[i];
    }
    __syncthreads();

    const int tid0 = blockIdx.x * 256 + threadIdx.x;
    const int f = tid0 & (FEAT - 1);
    // stride is a multiple of 128, so f is invariant across the grid-stride loop
    const float bv = bias[f];
    const float* col = s_cp + f;
    const int stride = gridDim.x * 256;

    for (int idx = tid0; idx < n; idx += stride) {
        float xx = x[idx];
        // Work in knot units: y = 61*x, knots T(i) = clamp(i-3,0,61).
        float y = xx * 61.0f;
        int j = (int)y;               // x >= 0 -> trunc == floor
        j = j > NSEG - 1 ? NSEG - 1 : j;  // span j in [0,60]

        float fj  = (float)j;
        float tm1 = (float)max(j - 1, 0);
        float tm2 = (float)max(j - 2, 0);
        float tp1 = fj + 1.0f;            // j+1 <= 61, never clamped
        float tp2 = (float)min(j + 2, NSEG);
        float tp3 = (float)min(j + 3, NSEG);

        float l1 = y - fj, l2 = y - tm1, l3 = y - tm2;
        float r1 = tp1 - y, r2 = tp2 - y, r3 = tp3 - y;

        // Local de Boor: the 4 nonzero cubic basis values N0..N3 at rows j..j+3.
        // degree 1 (denominator = tp1 - fj = 1)
        float N0 = r1, N1 = l1;
        // degree 2
        float t0 = N0 * rcp_fast(tp1 - tm1);
        N0 = r1 * t0;
        float sv = l2 * t0;
        float t1 = N1 * rcp_fast(tp2 - fj);
        N1 = sv + r2 * t1;
        float N2 = l1 * t1;
        // degree 3
        t0 = N0 * rcp_fast(tp1 - tm2);
        N0 = r1 * t0;
        sv = l3 * t0;
        t1 = N1 * rcp_fast(tp2 - tm1);
        N1 = sv + r2 * t1;
        sv = l2 * t1;
        float t2 = N2 * rcp_fast(tp3 - fj);
        N2 = sv + r3 * t2;
        float N3 = l1 * t2;

        float acc = N0 * col[j * FEAT]
                  + N1 * col[(j + 1) * FEAT]
                  + N2 * col[(j + 2) * FEAT]
                  + N3 * col[(j + 3) * FEAT];
        out[idx] = acc + bv;
    }
}

extern "C" void kernel_launch(void* const* d_in, const int* in_sizes, int n_in,
                              void* d_out, int out_size, void* d_ws, size_t ws_size,
                              hipStream_t stream) {
    const float* x    = (const float*)d_in[0];
    const float* cp   = (const float*)d_in[1];
    const float* bias = (const float*)d_in[2];
    float* out = (float*)d_out;
    int n = in_sizes[0];   // 16384*128 = 2,097,152 elements

    // 1024 blocks = 4 blocks/CU (LDS 32KB/block allows 5); 8 grid-stride iters.
    bspline_kernel<<<dim3(1024), dim3(256), 0, stream>>>(x, cp, bias, out, n);
}

// Round 2
// 67.376 us; speedup vs baseline: 1.0129x; 1.0129x over previous
//
#include <hip/hip_runtime.h>

#define NUM_KNOTS 64
#define FEAT 128
#define NSEG 61        // interior segments: knots j/61, j=0..61
#define LDS_STRIDE 65  // transposed [f][k] layout, k-stride 65 words (pad +1)

__device__ __forceinline__ float rcp_fast(float d) {
    // d is exactly 1.0f, 2.0f, or 3.0f; v_rcp_f32 exact for 1,2; ~1 ulp for 3.
    return __builtin_amdgcn_rcpf(d);
}

// colT points at s_cpT + f*LDS_STRIDE, so colT[k] == cp[k][f].
__device__ __forceinline__ float bspline_eval(float xx, const float* __restrict__ colT) {
    // Knot units: y = 61*x, knots T(i) = clamp(i-3, 0, 61).
    float y = xx * 61.0f;
    int j = (int)y;                    // x >= 0 -> trunc == floor
    j = j > NSEG - 1 ? NSEG - 1 : j;   // span j in [0,60]

    float fj  = (float)j;
    float tm1 = (float)max(j - 1, 0);
    float tm2 = (float)max(j - 2, 0);
    float tp1 = fj + 1.0f;             // never clamped (j+1 <= 61)
    float tp2 = (float)min(j + 2, NSEG);
    float tp3 = (float)min(j + 3, NSEG);

    float l1 = y - fj, l2 = y - tm1, l3 = y - tm2;
    float r1 = tp1 - y, r2 = tp2 - y, r3 = tp3 - y;

    // Local de Boor: 4 nonzero cubic basis values for rows j..j+3.
    float N0 = r1, N1 = l1;
    float t0 = N0 * rcp_fast(tp1 - tm1);
    N0 = r1 * t0;
    float sv = l2 * t0;
    float t1 = N1 * rcp_fast(tp2 - fj);
    N1 = sv + r2 * t1;
    float N2 = l1 * t1;
    t0 = N0 * rcp_fast(tp1 - tm2);
    N0 = r1 * t0;
    sv = l3 * t0;
    t1 = N1 * rcp_fast(tp2 - tm1);
    N1 = sv + r2 * t1;
    sv = l2 * t1;
    float t2 = N2 * rcp_fast(tp3 - fj);
    N2 = sv + r3 * t2;
    float N3 = l1 * t2;

    // 4 consecutive LDS words -> compiler fuses into ds_read2_b32 pairs.
    const float* c = colT + j;
    return N0 * c[0] + N1 * c[1] + N2 * c[2] + N3 * c[3];
}

__global__ __launch_bounds__(256, 4) void bspline_kernel(
    const float4* __restrict__ x4,
    const float*  __restrict__ cp,     // [64][128]
    const float*  __restrict__ bias,   // [128]
    float4* __restrict__ out4,
    int n4)
{
    // Transposed control points: s_cpT[f*65 + k] = cp[k][f].
    // Staging write bank = (f*65+k)%32 = (f+k)%32 -> lane-consecutive f =>
    // conflict-free. Read bank = (f+j+c)%32 with data-random j => ~uniform.
    __shared__ float s_cpT[FEAT * LDS_STRIDE];
    for (int u = threadIdx.x; u < NUM_KNOTS * FEAT; u += 256) {
        int f = u & (FEAT - 1);
        int k = u >> 7;
        s_cpT[f * LDS_STRIDE + k] = cp[u];
    }
    __syncthreads();

    const int tid = blockIdx.x * 256 + threadIdx.x;
    const int stride = gridDim.x * 256;
    const int f0 = (tid * 4) & (FEAT - 1);   // invariant: stride*4 % 128 == 0
    const float4 bv = *(const float4*)(bias + f0);
    const float* c0 = s_cpT + f0 * LDS_STRIDE;
    const float* c1 = c0 + LDS_STRIDE;
    const float* c2 = c1 + LDS_STRIDE;
    const float* c3 = c2 + LDS_STRIDE;

    int i = tid;
    // Pairwise: both global_load_dwordx4 in flight before either compute.
    for (; i + stride < n4; i += 2 * stride) {
        float4 xa = x4[i];
        float4 xb = x4[i + stride];
        float4 oa, ob;
        oa.x = bspline_eval(xa.x, c0) + bv.x;
        oa.y = bspline_eval(xa.y, c1) + bv.y;
        oa.z = bspline_eval(xa.z, c2) + bv.z;
        oa.w = bspline_eval(xa.w, c3) + bv.w;
        ob.x = bspline_eval(xb.x, c0) + bv.x;
        ob.y = bspline_eval(xb.y, c1) + bv.y;
        ob.z = bspline_eval(xb.z, c2) + bv.z;
        ob.w = bspline_eval(xb.w, c3) + bv.w;
        out4[i] = oa;
        out4[i + stride] = ob;
    }
    for (; i < n4; i += stride) {   // tail (not taken for n4=524288, grid=262144)
        float4 xv = x4[i];
        float4 ov;
        ov.x = bspline_eval(xv.x, c0) + bv.x;
        ov.y = bspline_eval(xv.y, c1) + bv.y;
        ov.z = bspline_eval(xv.z, c2) + bv.z;
        ov.w = bspline_eval(xv.w, c3) + bv.w;
        out4[i] = ov;
    }
}

extern "C" void kernel_launch(void* const* d_in, const int* in_sizes, int n_in,
                              void* d_out, int out_size, void* d_ws, size_t ws_size,
                              hipStream_t stream) {
    const float* x    = (const float*)d_in[0];
    const float* cp   = (const float*)d_in[1];
    const float* bias = (const float*)d_in[2];
    float* out = (float*)d_out;
    int n = in_sizes[0];      // 16384*128 = 2,097,152
    int n4 = n >> 2;          // 524,288 float4 elements

    // 1024 blocks * 256 thr = 262144 threads -> exactly one paired iteration.
    // 4 blocks/CU (32.5 KB LDS each), 16 waves/CU.
    bspline_kernel<<<dim3(1024), dim3(256), 0, stream>>>(
        (const float4*)x, cp, bias, (float4*)out, n4);
}

// Round 3
// 66.193 us; speedup vs baseline: 1.0310x; 1.0179x over previous
//
#include <hip/hip_runtime.h>

#define NUM_KNOTS 64
#define FEAT 128
#define NSEG 61        // interior segments: knots j/61, j=0..61
#define LDS_STRIDE 65  // transposed [f][k] layout, k-stride 65 words (pad +1)

__device__ __forceinline__ float rcp_fast(float d) {
    // d is exactly 1.0f, 2.0f, or 3.0f; v_rcp_f32 exact for 1,2; ~1 ulp for 3.
    return __builtin_amdgcn_rcpf(d);
}

// colT points at s_cpT + f*LDS_STRIDE, so colT[k] == cp[k][f].
__device__ __forceinline__ float bspline_eval(float xx, const float* __restrict__ colT) {
    // Knot units: y = 61*x, knots T(i) = clamp(i-3, 0, 61).
    float y = xx * 61.0f;
    int j = (int)y;                    // x >= 0 -> trunc == floor
    j = j > NSEG - 1 ? NSEG - 1 : j;   // span j in [0,60]

    float fj  = (float)j;
    float tm1 = (float)max(j - 1, 0);
    float tm2 = (float)max(j - 2, 0);
    float tp1 = fj + 1.0f;             // never clamped (j+1 <= 61)
    float tp2 = (float)min(j + 2, NSEG);
    float tp3 = (float)min(j + 3, NSEG);

    float l1 = y - fj, l2 = y - tm1, l3 = y - tm2;
    float r1 = tp1 - y, r2 = tp2 - y, r3 = tp3 - y;

    // Local de Boor: 4 nonzero cubic basis values for rows j..j+3.
    float N0 = r1, N1 = l1;
    float t0 = N0 * rcp_fast(tp1 - tm1);
    N0 = r1 * t0;
    float sv = l2 * t0;
    float t1 = N1 * rcp_fast(tp2 - fj);
    N1 = sv + r2 * t1;
    float N2 = l1 * t1;
    t0 = N0 * rcp_fast(tp1 - tm2);
    N0 = r1 * t0;
    sv = l3 * t0;
    t1 = N1 * rcp_fast(tp2 - tm1);
    N1 = sv + r2 * t1;
    sv = l2 * t1;
    float t2 = N2 * rcp_fast(tp3 - fj);
    N2 = sv + r3 * t2;
    float N3 = l1 * t2;

    // 4 consecutive LDS words -> ds_read2_b32 pairs.
    const float* c = colT + j;
    return N0 * c[0] + N1 * c[1] + N2 * c[2] + N3 * c[3];
}

__global__ __launch_bounds__(256, 4) void bspline_kernel(
    const float4* __restrict__ x4,
    const float*  __restrict__ cp,     // [64][128]
    const float*  __restrict__ bias,   // [128]
    float4* __restrict__ out4,
    int n4)
{
    __shared__ float s_cpT[FEAT * LDS_STRIDE];

    const int tid = blockIdx.x * 256 + threadIdx.x;
    const int stride = gridDim.x * 256;

    // Prefetch the first pair of x vectors BEFORE staging, so the HBM read
    // latency overlaps the cp->LDS staging and the barrier.
    int i0 = tid;
    int i1 = tid + stride;
    float4 xa = x4[i0];
    float4 xb = x4[i1];

    // Transposed control points: s_cpT[f*65 + k] = cp[k][f].
    // Staging write bank = (f+k)%32 -> lane-consecutive u => conflict-free-ish.
    for (int u = threadIdx.x; u < NUM_KNOTS * FEAT; u += 256) {
        int f = u & (FEAT - 1);
        int k = u >> 7;
        s_cpT[f * LDS_STRIDE + k] = cp[u];
    }
    __syncthreads();

    const int f0 = (tid * 4) & (FEAT - 1);   // invariant across grid-stride
    const float4 bv = *(const float4*)(bias + f0);
    const float* c0 = s_cpT + f0 * LDS_STRIDE;
    const float* c1 = c0 + LDS_STRIDE;
    const float* c2 = c1 + LDS_STRIDE;
    const float* c3 = c2 + LDS_STRIDE;

    while (true) {
        // Issue next pair's loads before computing on the current pair.
        int n0 = i1 + stride;
        int n1 = n0 + stride;
        bool more = n1 < n4;        // pairs always complete: n4 % (2*stride) == 0
        float4 xc, xd;
        if (more) { xc = x4[n0]; xd = x4[n1]; }

        float4 oa, ob;
        oa.x = bspline_eval(xa.x, c0) + bv.x;
        oa.y = bspline_eval(xa.y, c1) + bv.y;
        oa.z = bspline_eval(xa.z, c2) + bv.z;
        oa.w = bspline_eval(xa.w, c3) + bv.w;
        ob.x = bspline_eval(xb.x, c0) + bv.x;
        ob.y = bspline_eval(xb.y, c1) + bv.y;
        ob.z = bspline_eval(xb.z, c2) + bv.z;
        ob.w = bspline_eval(xb.w, c3) + bv.w;
        out4[i0] = oa;
        out4[i1] = ob;

        if (!more) break;
        i0 = n0; i1 = n1; xa = xc; xb = xd;
    }
}

extern "C" void kernel_launch(void* const* d_in, const int* in_sizes, int n_in,
                              void* d_out, int out_size, void* d_ws, size_t ws_size,
                              hipStream_t stream) {
    const float* x    = (const float*)d_in[0];
    const float* cp   = (const float*)d_in[1];
    const float* bias = (const float*)d_in[2];
    float* out = (float*)d_out;
    int n = in_sizes[0];      // 16384*128 = 2,097,152
    int n4 = n >> 2;          // 524,288 float4 elements

    // 512 blocks = 2/CU: halves aggregate cp staging (16 MB), each thread
    // processes 4 float4 (2 paired iterations) to amortize the staging cost.
    bspline_kernel<<<dim3(512), dim3(256), 0, stream>>>(
        (const float4*)x, cp, bias, (float4*)out, n4);
}